// Round 6
// baseline (107.545 us; speedup 1.0000x reference)
//
#include <hip/hip_runtime.h>
#include <float.h>
#include <math.h>

// B=65536 rows, C=1000 cols, fp32. One wave (64 lanes) per row, persistent
// grid-stride waves. R6 structural fixes:
//  (1) UNCONDITIONAL clamped prefetch (no branch around the next-row loads) so
//      the compiler emits a counted s_waitcnt (vmcnt(5)) instead of vmcnt(0) —
//      next-row HBM loads stay in flight across the current row's compute.
//  (2) Online-softmax merged reduction: per-lane local max m_l, local
//      S_l=sum exp(x-m_l), W_l=sum exp(x-m_l)*x start immediately (no
//      cross-lane dependency); ONE 6-step butterfly merges (m,S,W) with
//      rescaling + sums L. Serial DS depth per row: 18 -> 12 steps.
//      H_hat = W/S - m - log S is exact for ANY finite m, so no overflow:
//      merge uses exp(m_i - m_new) <= 1.
// Config: grid 2048 x 256 (R3 best), wL cached in 16 VGPRs/wave.

static constexpr int   kC4    = 250;   // float4 per row (1000 floats)
static constexpr int   kBlock = 256;   // 4 waves per block
static constexpr int   kGrid  = 2048;  // 8192 waves -> 8 rows/wave at B=65536
static constexpr int   kWavesTotal = kGrid * (kBlock / 64);
static constexpr float kEps   = 1.1920928955078125e-07f;  // FLT_EPSILON
static constexpr float kLogC  = 6.907755279f;             // ln(1000)

__device__ __forceinline__ float wred_sum(float v) {
#pragma unroll
  for (int off = 32; off > 0; off >>= 1) v += __shfl_xor(v, off, 64);
  return v;
}

__device__ __forceinline__ void p1_local(const float4 c, const float4 w,
                                         float& L, float& m) {
  L = fmaf(c.x, w.x, L); L = fmaf(c.y, w.y, L);
  L = fmaf(c.z, w.z, L); L = fmaf(c.w, w.w, L);
  m = fmaxf(m, fmaxf(fmaxf(c.x, c.y), fmaxf(c.z, c.w)));
}
__device__ __forceinline__ void p2_local(const float4 c, const float m,
                                         float& S, float& W) {
  float e;
  e = __expf(c.x - m); S += e; W = fmaf(e, c.x, W);
  e = __expf(c.y - m); S += e; W = fmaf(e, c.y, W);
  e = __expf(c.z - m); S += e; W = fmaf(e, c.z, W);
  e = __expf(c.w - m); S += e; W = fmaf(e, c.w, W);
}
__device__ __forceinline__ void p3_sumexp2(const float4 c, const float rT,
                                           const float nmrT, float& S2) {
  S2 += __expf(fmaf(c.x, rT, nmrT)); S2 += __expf(fmaf(c.y, rT, nmrT));
  S2 += __expf(fmaf(c.z, rT, nmrT)); S2 += __expf(fmaf(c.w, rT, nmrT));
}

#define SENT4 make_float4(-FLT_MAX, -FLT_MAX, -FLT_MAX, -FLT_MAX)

__global__ __launch_bounds__(kBlock) void ats_row_kernel(
    const float* __restrict__ X, const int* __restrict__ labels,
    const float* __restrict__ wL, const float* __restrict__ wH,
    const float* __restrict__ bb, double* __restrict__ partial, int B) {
  const int lane   = threadIdx.x & 63;
  const int wib    = threadIdx.x >> 6;                    // wave in block
  const int wid    = blockIdx.x * (kBlock / 64) + wib;    // global wave id
  const bool tailok = lane < (kC4 - 192);                 // lanes 0..57

  // wL cached once per wave (row-invariant), 16 VGPRs
  const float4* WLr = reinterpret_cast<const float4*>(wL);
  const float4 w0 = WLr[lane];
  const float4 w1 = WLr[64 + lane];
  const float4 w2 = WLr[128 + lane];
  const float4 w3 = tailok ? WLr[192 + lane] : make_float4(0.f, 0.f, 0.f, 0.f);
  const float wH0 = wH[0];
  const float b0  = bb[0];

  double acc = 0.0;

  // ---- prefetch first row (wid < kWavesTotal <= B always)
  int row = wid;
  float4 c0, c1, c2, c3;
  int labc;
  {
    const float4* Xr = reinterpret_cast<const float4*>(X) + (size_t)row * kC4;
    c0 = Xr[lane]; c1 = Xr[64 + lane]; c2 = Xr[128 + lane];
    c3 = tailok ? Xr[192 + lane] : SENT4;
    labc = labels[row];
  }

  for (; row < B; row += kWavesTotal) {
    // ---- UNCONDITIONAL clamped prefetch of next row: no branch -> compiler
    // can use a counted vmcnt, keeping these loads in flight across compute.
    const int nrow = row + kWavesTotal;
    const int prow = (nrow < B) ? nrow : (B - 1);   // clamp, still uniform
    float4 n0, n1, n2, n3;
    int labn;
    {
      const float4* Xn = reinterpret_cast<const float4*>(X) + (size_t)prow * kC4;
      n0 = Xn[lane]; n1 = Xn[64 + lane]; n2 = Xn[128 + lane];
      n3 = tailok ? Xn[192 + lane] : SENT4;
      labn = labels[prow];
    }

    // ---- local pass: per-lane max, dot, then immediately local S,W
    // (no cross-lane dependency before the exps)
    float L = 0.f, ml = -FLT_MAX;
    p1_local(c0, w0, L, ml); p1_local(c1, w1, L, ml);
    p1_local(c2, w2, L, ml); p1_local(c3, w3, L, ml);
    // ml is finite: every lane has >=12 real elements (c0..c2).
    float S = 0.f, W = 0.f;
    p2_local(c0, ml, S, W); p2_local(c1, ml, S, W);
    p2_local(c2, ml, S, W); p2_local(c3, ml, S, W);
    // sentinel elems: exp(-FLT_MAX - ml) -> 0, 0*finite = 0 contribution.

    // ---- ONE merged butterfly: (m, S, W) online-softmax merge + L sum
#pragma unroll
    for (int off = 32; off > 0; off >>= 1) {
      const float mo = __shfl_xor(ml, off, 64);
      const float So = __shfl_xor(S,  off, 64);
      const float Wo = __shfl_xor(W,  off, 64);
      const float Lo = __shfl_xor(L,  off, 64);
      const float mn = fmaxf(ml, mo);
      const float ea = __expf(ml - mn);   // <= 1
      const float eb = __expf(mo - mn);   // <= 1
      S  = fmaf(S, ea, So * eb);
      W  = fmaf(W, ea, Wo * eb);
      L += Lo;
      ml = mn;
    }
    const float m = ml;  // all lanes uniform now

    // ---- x[label]: slot/elem are wave-uniform, one shfl broadcast
    const int c4l = labc >> 2;
    const int sl  = c4l >> 6, ln = c4l & 63, el = labc & 3;
    float4 v = (sl == 0) ? c0 : (sl == 1) ? c1 : (sl == 2) ? c2 : c3;
    float cand = (el == 0) ? v.x : (el == 1) ? v.y : (el == 2) ? v.z : v.w;
    const float xl = __shfl(cand, ln, 64);

    // ---- temperature (H_hat exact for any m: W/S - m - log S)
    const float Hhat = W / S - m - __logf(S);
    const float a    = L + wH0 * (Hhat / kLogC) + b0;
    const float sp   = (a > 0.f) ? (a + log1pf(__expf(-a))) : log1pf(__expf(a));
    const float T    = fmaxf(sp, kEps);
    const float rT   = 1.0f / T;
    const float nmrT = -m * rT;

    // ---- pass3: S2 = sum exp((x-m)/T)  (registers only)
    float S2 = 0.f;
    p3_sumexp2(c0, rT, nmrT, S2); p3_sumexp2(c1, rT, nmrT, S2);
    p3_sumexp2(c2, rT, nmrT, S2); p3_sumexp2(c3, rT, nmrT, S2);
    S2 = wred_sum(S2);

    const float nll = __logf(S2) - fmaf(xl, rT, nmrT);  // logS2 - (xl-m)/T
    acc += (double)nll;

    // ---- rotate pipeline
    c0 = n0; c1 = n1; c2 = n2; c3 = n3; labc = labn;
  }

  // ---- block partial (all lanes hold identical acc; lane 0 per wave writes)
  __shared__ double sacc[kBlock / 64];
  if (lane == 0) sacc[wib] = acc;
  __syncthreads();
  if (threadIdx.x == 0)
    partial[blockIdx.x] = (sacc[0] + sacc[1]) + (sacc[2] + sacc[3]);
}

__global__ __launch_bounds__(256) void ats_final_kernel(
    const double* __restrict__ partial, float* __restrict__ out, int n, int B) {
  __shared__ double sdata[256];
  double a = 0.0;
  for (int i = threadIdx.x; i < n; i += 256) a += partial[i];
  sdata[threadIdx.x] = a;
  __syncthreads();
#pragma unroll
  for (int s = 128; s > 0; s >>= 1) {
    if ((int)threadIdx.x < s) sdata[threadIdx.x] += sdata[threadIdx.x + s];
    __syncthreads();
  }
  if (threadIdx.x == 0) out[0] = (float)(sdata[0] / (double)B);
}

extern "C" void kernel_launch(void* const* d_in, const int* in_sizes, int n_in,
                              void* d_out, int out_size, void* d_ws, size_t ws_size,
                              hipStream_t stream) {
  (void)n_in; (void)out_size; (void)ws_size;
  const float* X   = (const float*)d_in[0];
  const int*   lab = (const int*)d_in[1];
  const float* wL  = (const float*)d_in[2];
  const float* wH  = (const float*)d_in[3];
  const float* bb  = (const float*)d_in[4];
  const int B = in_sizes[1];            // 65536 labels
  double* partial = (double*)d_ws;      // kGrid doubles = 16 KB scratch
  float* out = (float*)d_out;

  ats_row_kernel<<<kGrid, kBlock, 0, stream>>>(X, lab, wL, wH, bb, partial, B);
  ats_final_kernel<<<1, 256, 0, stream>>>(partial, out, kGrid, B);
}

// Round 7
// 106.758 us; speedup vs baseline: 1.0074x; 1.0074x over previous
//
#include <hip/hip_runtime.h>
#include <float.h>
#include <math.h>

// B=65536 rows, C=1000 cols, fp32. One wave (64 lanes) per row, persistent
// grid-stride waves with next-row register prefetch (software pipeline).
// R7 = R3 verbatim with EXACTLY ONE change: the next-row prefetch is
// UNCONDITIONAL with a clamped row index (min(nrow, B-1)) instead of being
// guarded by `if (nrow < B)`. A/B test of the waitcnt-join theory: the
// branch made outstanding-load counts path-dependent, forcing a conservative
// s_waitcnt vmcnt(0) before the row's compute (serializing HBM latency);
// the clamp lets the wait sink to the register-rotate at loop bottom.
// Per row (X read from HBM exactly once, row lives in 16 VGPRs/lane):
//   pass1: m = max(x), L = dot(x, wL)        (wL cached in 16 VGPRs per wave)
//   pass2: S = sum exp(x-m), W = sum exp(x-m)*x
//   H_hat = W/S - m - log S ;  T = clip(softplus(L + wH*H_hat/lnC + b), EPS)
//   pass3 (regs only): S2 = sum exp((x-m)/T); nll = log S2 - (x_lab - m)/T
// Mean: per-block double partial -> d_ws, tiny final kernel (2048 vals).

static constexpr int   kC4    = 250;   // float4 per row (1000 floats)
static constexpr int   kBlock = 256;   // 4 waves per block
static constexpr int   kGrid  = 2048;  // 8192 waves -> 8 rows/wave at B=65536
static constexpr int   kWavesTotal = kGrid * (kBlock / 64);
static constexpr float kEps   = 1.1920928955078125e-07f;  // FLT_EPSILON
static constexpr float kLogC  = 6.907755279f;             // ln(1000)

__device__ __forceinline__ float wred_max(float v) {
#pragma unroll
  for (int off = 32; off > 0; off >>= 1) v = fmaxf(v, __shfl_xor(v, off, 64));
  return v;
}
__device__ __forceinline__ float wred_sum(float v) {
#pragma unroll
  for (int off = 32; off > 0; off >>= 1) v += __shfl_xor(v, off, 64);
  return v;
}

__device__ __forceinline__ void p1_dot_max(const float4 c, const float4 w,
                                           float& L, float& m) {
  L = fmaf(c.x, w.x, L); L = fmaf(c.y, w.y, L);
  L = fmaf(c.z, w.z, L); L = fmaf(c.w, w.w, L);
  m = fmaxf(m, fmaxf(fmaxf(c.x, c.y), fmaxf(c.z, c.w)));
}
__device__ __forceinline__ void p2_sumexp(const float4 c, const float m,
                                          float& S, float& W) {
  float e;
  e = __expf(c.x - m); S += e; W = fmaf(e, c.x, W);
  e = __expf(c.y - m); S += e; W = fmaf(e, c.y, W);
  e = __expf(c.z - m); S += e; W = fmaf(e, c.z, W);
  e = __expf(c.w - m); S += e; W = fmaf(e, c.w, W);
}
__device__ __forceinline__ void p3_sumexp2(const float4 c, const float rT,
                                           const float nmrT, float& S2) {
  S2 += __expf(fmaf(c.x, rT, nmrT)); S2 += __expf(fmaf(c.y, rT, nmrT));
  S2 += __expf(fmaf(c.z, rT, nmrT)); S2 += __expf(fmaf(c.w, rT, nmrT));
}

#define SENT4 make_float4(-FLT_MAX, -FLT_MAX, -FLT_MAX, -FLT_MAX)

__global__ __launch_bounds__(kBlock) void ats_row_kernel(
    const float* __restrict__ X, const int* __restrict__ labels,
    const float* __restrict__ wL, const float* __restrict__ wH,
    const float* __restrict__ bb, double* __restrict__ partial, int B) {
  const int lane   = threadIdx.x & 63;
  const int wib    = threadIdx.x >> 6;                    // wave in block
  const int wid    = blockIdx.x * (kBlock / 64) + wib;    // global wave id
  const bool tailok = lane < (kC4 - 192);                 // lanes 0..57

  // wL cached once per wave (row-invariant), 16 VGPRs
  const float4* WLr = reinterpret_cast<const float4*>(wL);
  const float4 w0 = WLr[lane];
  const float4 w1 = WLr[64 + lane];
  const float4 w2 = WLr[128 + lane];
  const float4 w3 = tailok ? WLr[192 + lane] : make_float4(0.f, 0.f, 0.f, 0.f);
  const float wH0 = wH[0];
  const float b0  = bb[0];

  double acc = 0.0;

  // ---- prefetch first row (wid < kWavesTotal <= B always)
  int row = wid;
  float4 c0, c1, c2, c3;
  int labc;
  {
    const float4* Xr = reinterpret_cast<const float4*>(X) + (size_t)row * kC4;
    c0 = Xr[lane]; c1 = Xr[64 + lane]; c2 = Xr[128 + lane];
    c3 = tailok ? Xr[192 + lane] : SENT4;
    labc = labels[row];
  }

  for (; row < B; row += kWavesTotal) {
    // ---- UNCONDITIONAL clamped prefetch (the single change vs R3)
    const int nrow = row + kWavesTotal;
    const int prow = (nrow < B) ? nrow : (B - 1);
    float4 n0, n1, n2, n3;
    int labn;
    {
      const float4* Xn = reinterpret_cast<const float4*>(X) + (size_t)prow * kC4;
      n0 = Xn[lane]; n1 = Xn[64 + lane]; n2 = Xn[128 + lane];
      n3 = tailok ? Xn[192 + lane] : SENT4;
      labn = labels[prow];
    }

    // ---- pass1: max + dot (sentinel -FLT_MAX never wins max; w3=0 on tail)
    float L = 0.f, m = -FLT_MAX;
    p1_dot_max(c0, w0, L, m); p1_dot_max(c1, w1, L, m);
    p1_dot_max(c2, w2, L, m); p1_dot_max(c3, w3, L, m);
    m = wred_max(m);

    // ---- pass2: S = sum e, W = sum e*x  (exp underflows to 0 on sentinel)
    float S = 0.f, W = 0.f;
    p2_sumexp(c0, m, S, W); p2_sumexp(c1, m, S, W);
    p2_sumexp(c2, m, S, W); p2_sumexp(c3, m, S, W);
    S = wred_sum(S);
    W = wred_sum(W);
    L = wred_sum(L);

    // ---- x[label]: slot/elem are wave-uniform, one shfl broadcast
    const int c4l = labc >> 2;
    const int sl  = c4l >> 6, ln = c4l & 63, el = labc & 3;
    float4 v = (sl == 0) ? c0 : (sl == 1) ? c1 : (sl == 2) ? c2 : c3;
    float cand = (el == 0) ? v.x : (el == 1) ? v.y : (el == 2) ? v.z : v.w;
    const float xl = __shfl(cand, ln, 64);

    // ---- temperature
    const float Hhat = W / S - m - __logf(S);
    const float a    = L + wH0 * (Hhat / kLogC) + b0;
    const float sp   = (a > 0.f) ? (a + log1pf(__expf(-a))) : log1pf(__expf(a));
    const float T    = fmaxf(sp, kEps);
    const float rT   = 1.0f / T;
    const float nmrT = -m * rT;

    // ---- pass3: S2 = sum exp((x-m)/T)  (registers only)
    float S2 = 0.f;
    p3_sumexp2(c0, rT, nmrT, S2); p3_sumexp2(c1, rT, nmrT, S2);
    p3_sumexp2(c2, rT, nmrT, S2); p3_sumexp2(c3, rT, nmrT, S2);
    S2 = wred_sum(S2);

    const float nll = __logf(S2) - fmaf(xl, rT, nmrT);  // logS2 - (xl-m)/T
    acc += (double)nll;

    // ---- rotate pipeline
    c0 = n0; c1 = n1; c2 = n2; c3 = n3; labc = labn;
  }

  // ---- block partial (all lanes hold identical acc; lane 0 per wave writes)
  __shared__ double sacc[kBlock / 64];
  if (lane == 0) sacc[wib] = acc;
  __syncthreads();
  if (threadIdx.x == 0)
    partial[blockIdx.x] = (sacc[0] + sacc[1]) + (sacc[2] + sacc[3]);
}

__global__ __launch_bounds__(256) void ats_final_kernel(
    const double* __restrict__ partial, float* __restrict__ out, int n, int B) {
  __shared__ double sdata[256];
  double a = 0.0;
  for (int i = threadIdx.x; i < n; i += 256) a += partial[i];
  sdata[threadIdx.x] = a;
  __syncthreads();
#pragma unroll
  for (int s = 128; s > 0; s >>= 1) {
    if ((int)threadIdx.x < s) sdata[threadIdx.x] += sdata[threadIdx.x + s];
    __syncthreads();
  }
  if (threadIdx.x == 0) out[0] = (float)(sdata[0] / (double)B);
}

extern "C" void kernel_launch(void* const* d_in, const int* in_sizes, int n_in,
                              void* d_out, int out_size, void* d_ws, size_t ws_size,
                              hipStream_t stream) {
  (void)n_in; (void)out_size; (void)ws_size;
  const float* X   = (const float*)d_in[0];
  const int*   lab = (const int*)d_in[1];
  const float* wL  = (const float*)d_in[2];
  const float* wH  = (const float*)d_in[3];
  const float* bb  = (const float*)d_in[4];
  const int B = in_sizes[1];            // 65536 labels
  double* partial = (double*)d_ws;      // kGrid doubles = 16 KB scratch
  float* out = (float*)d_out;

  ats_row_kernel<<<kGrid, kBlock, 0, stream>>>(X, lab, wL, wH, bb, partial, B);
  ats_final_kernel<<<1, 256, 0, stream>>>(partial, out, kGrid, B);
}